// Round 15
// baseline (372.934 us; speedup 1.0000x reference)
//
#include <hip/hip_runtime.h>
#include <hip/hip_fp16.h>
#include <stdint.h>

#define BATCH 16
#define NPTS  8192
#define KNN   16
#define NROWS (BATCH*NPTS)     // 131072
#define EPSBN 1e-5f
#define DEGINV (1.0f/17.0f)

typedef _Float16 f16x8 __attribute__((ext_vector_type(8)));
typedef float    f32x4 __attribute__((ext_vector_type(4)));

__device__ __forceinline__ unsigned short f2hu(float f) {
    union { _Float16 h; unsigned short u; } cv;
    cv.h = (_Float16)f;
    return cv.u;
}
__device__ __forceinline__ float hu2f(unsigned short u) {
    union { unsigned short u; _Float16 h; } cv;
    cv.u = u;
    return (float)cv.h;
}
// order-preserving float <-> uint encoding (for atomic min/max)
__device__ __forceinline__ unsigned fenc(float f) {
    unsigned u = __float_as_uint(f);
    return (int)u >= 0 ? (u | 0x80000000u) : ~u;
}
__device__ __forceinline__ float fdec(unsigned k) {
    return (k & 0x80000000u) ? __uint_as_float(k & 0x7FFFFFFFu) : __uint_as_float(~k);
}

// stats zone layout (floats):
#define SZ_S1    0        // stats1: 64 sum + 64 sumsq
#define SZ_S2P   128      // stats2p: 64 x (128+128)
#define SZ_S3P   16512    // stats3p: 64 x (512+512)
#define SZ_S4    82048    // stats4: 512+512
#define SZ_C1    83072
#define SZ_GN    83080
#define SZ_D2    83088
#define SZ_SCSH1 83096    // 2*64
#define SZ_SCSH2 83224    // 2*128
#define SZ_TOT   83480

// mm zone: [0,8192) max enc, [8192,16384) min enc, [16384] cnt1, [16385] cnt2

// ---------------------------------------------------------------------------
// k_prep: zero stats+counters, init min/max sentinels, fp16 W^T copies,
// grid feats, xyz -> float4-padded data4
// ---------------------------------------------------------------------------
__global__ __launch_bounds__(256) void k_prep(
    const float* __restrict__ data, const float* __restrict__ gc1w,
    const float* __restrict__ gc2w,
    const float* __restrict__ d1w, const float* __restrict__ d1b,
    unsigned short* __restrict__ W1T, unsigned short* __restrict__ W2T,
    float* __restrict__ gn, float* __restrict__ statszone, unsigned* __restrict__ mm,
    float4* __restrict__ data4)
{
    int t = blockIdx.x * 256 + threadIdx.x;
    int NT_ = gridDim.x * 256;
    for (int i = t; i < 65536; i += NT_) {          // W2T[c][k] = gc2_w[k][c]
        int c = i >> 7, k = i & 127;
        W2T[i] = f2hu(gc2w[k * 512 + c]);
    }
    for (int i = t; i < 8192; i += NT_) {           // W1T[c][k] = gc1_w[k][c]
        int c = i >> 6, k = i & 63;
        W1T[i] = f2hu(gc1w[k * 128 + c]);
    }
    for (int i = t; i < SZ_TOT; i += NT_) statszone[i] = 0.f;
    for (int i = t; i < 8192; i += NT_) mm[i] = 0u;                 // max enc
    for (int i = t; i < 8192; i += NT_) mm[8192 + i] = 0xFFFFFFFFu; // min enc
    if (t < 2) mm[16384 + t] = 0u;                                  // counters
    for (int i = t; i < NROWS; i += NT_) {
        float4 v;
        v.x = data[(size_t)i * 3 + 0];
        v.y = data[(size_t)i * 3 + 1];
        v.z = data[(size_t)i * 3 + 2];
        v.w = 0.f;
        data4[i] = v;
    }
    for (int n = t; n < 8192; n += NT_) {
        int ix = n / 65, iy = n % 65;
        float gx = 1.f + ix * (119.f / 128.f);
        float gy = 1.f + iy * (59.f / 64.f);
        #pragma unroll
        for (int j = 0; j < 3; j++)
            gn[n * 3 + j] = gx * d1w[512 * 3 + j] + gy * d1w[513 * 3 + j] + d1b[j];
    }
}

// ---------------------------------------------------------------------------
// k_cov_e1: covariance features + Linear(12,64) -> a1 [131072][64] fp16
// ---------------------------------------------------------------------------
__global__ __launch_bounds__(256) void k_cov_e1(
    const float4* __restrict__ data4, const int* __restrict__ knn,
    const float* __restrict__ e1w, const float* __restrict__ e1b,
    unsigned short* __restrict__ a1)
{
    __shared__ float w[12 * 64];
    __shared__ float bias[64];
    int tid = threadIdx.x;
    for (int i = tid; i < 768; i += 256) w[i] = e1w[i];
    if (tid < 64) bias[tid] = e1b[tid];
    __syncthreads();

    int gid = blockIdx.x * 256 + tid;
    int b = gid >> 13;
    const float4* db4 = data4 + (size_t)b * NPTS;
    const int4* k4 = (const int4*)knn + gid * 4;

    float sx = 0, sy = 0, sz = 0, Sxx = 0, Sxy = 0, Sxz = 0, Syy = 0, Syz = 0, Szz = 0;
    #pragma unroll
    for (int jj = 0; jj < 4; jj++) {
        int4 q = k4[jj];
        int id[4] = {q.x, q.y, q.z, q.w};
        #pragma unroll
        for (int u = 0; u < 4; u++) {
            float4 p = db4[id[u]];
            float x = p.x, y = p.y, z = p.z;
            sx += x; sy += y; sz += z;
            Sxx += x * x; Sxy += x * y; Sxz += x * z;
            Syy += y * y; Syz += y * z; Szz += z * z;
        }
    }
    float mx = sx * (1.f / 16.f), my = sy * (1.f / 16.f), mz = sz * (1.f / 16.f);
    const float inv15 = 1.f / 15.f;
    float4 self = data4[gid];
    float x12[12];
    x12[0] = self.x;
    x12[1] = self.y;
    x12[2] = self.z;
    x12[3] = (Sxx - 16.f * mx * mx) * inv15;
    x12[4] = (Sxy - 16.f * mx * my) * inv15;
    x12[5] = (Sxz - 16.f * mx * mz) * inv15;
    x12[6] = x12[4];
    x12[7] = (Syy - 16.f * my * my) * inv15;
    x12[8] = (Syz - 16.f * my * mz) * inv15;
    x12[9] = x12[5];
    x12[10] = x12[8];
    x12[11] = (Szz - 16.f * mz * mz) * inv15;

    unsigned short* arow = a1 + (size_t)gid * 64;
    for (int c0 = 0; c0 < 64; c0 += 8) {
        float v8[8];
        #pragma unroll
        for (int u = 0; u < 8; u++) {
            int c = c0 + u;
            float acc = bias[c];
            #pragma unroll
            for (int i = 0; i < 12; i++) acc += x12[i] * w[i * 64 + c];
            v8[u] = acc;
        }
        uint4 o;
        o.x = f2hu(v8[0]) | ((unsigned)f2hu(v8[1]) << 16);
        o.y = f2hu(v8[2]) | ((unsigned)f2hu(v8[3]) << 16);
        o.z = f2hu(v8[4]) | ((unsigned)f2hu(v8[5]) << 16);
        o.w = f2hu(v8[6]) | ((unsigned)f2hu(v8[7]) << 16);
        *(uint4*)(arow + c0) = o;
    }
}

// ---------------------------------------------------------------------------
// k_reduce_a1: per-channel sum/sumsq of fp16 a1 -> stats1; LAST block also
// computes scsh1 (fused bncoef, device-scope counter handshake)
// ---------------------------------------------------------------------------
__global__ __launch_bounds__(256) void k_reduce_a1(
    const unsigned short* __restrict__ a1, float* __restrict__ stats1,
    const float* __restrict__ gamma, const float* __restrict__ beta,
    float* __restrict__ scsh, unsigned* __restrict__ counter)
{
    int tid = threadIdx.x;
    int c = tid & 63, rq = tid >> 6;
    float s = 0.f, q = 0.f;
    for (int row = blockIdx.x * 4 + rq; row < NROWS; row += gridDim.x * 4) {
        float v = hu2f(a1[(size_t)row * 64 + c]);
        s += v; q += v * v;
    }
    __shared__ float red[2][256];
    red[0][tid] = s; red[1][tid] = q;
    __syncthreads();
    if (tid < 64) {
        s = red[0][tid] + red[0][tid + 64] + red[0][tid + 128] + red[0][tid + 192];
        q = red[1][tid] + red[1][tid + 64] + red[1][tid + 128] + red[1][tid + 192];
        atomicAdd(stats1 + tid, s);
        atomicAdd(stats1 + 64 + tid, q);
    }
    __syncthreads();                      // drains wave0's atomics (vmcnt before barrier)
    __shared__ bool last;
    if (tid == 0) {
        __threadfence();
        last = (atomicAdd(counter, 1u) == (unsigned)gridDim.x - 1u);
    }
    __syncthreads();
    if (last && tid < 64) {
        float ss = atomicAdd(stats1 + tid, 0.f);        // coherent read
        float qq = atomicAdd(stats1 + 64 + tid, 0.f);
        float m = ss * (1.f / NROWS);
        float var = fmaxf(qq * (1.f / NROWS) - m * m, 0.f);
        float sc = gamma[tid] * rsqrtf(var + EPSBN);
        scsh[tid] = sc;
        scsh[64 + tid] = beta[tid] - m * sc;
    }
}

// ---------------------------------------------------------------------------
// k_gather16: s[row] = bn_relu(a[row]) + sum_j bn_relu(a[knn_j]) -> fp16
// TWO rows per thread (independent chains, 34 x 16-B loads in flight).
// ---------------------------------------------------------------------------
template <int CIN>
__global__ __launch_bounds__(256) void k_gather16(
    const unsigned short* __restrict__ ain, const int* __restrict__ knn,
    const float* __restrict__ scsh, unsigned short* __restrict__ S)
{
    constexpr int GPR = CIN / 8;            // threads per row
    constexpr int R = 256 / GPR;            // rows per pass
    constexpr int R2 = 2 * R;               // rows per block
    constexpr int BPB = NPTS / R2;          // blocks per batch

    __shared__ int nidx[R2 * KNN];

    int tid = threadIdx.x;
    int blk = blockIdx.x;
    int xcd = blk & 7;
    int idx = blk >> 3;
    int batch = xcd + 8 * (idx / BPB);
    int within = idx % BPB;
    int node0 = batch * NPTS + within * R2;

    {
        const int4* ksrc = (const int4*)(knn + (size_t)node0 * KNN);
        for (int i = tid; i < R2 * 4; i += 256) ((int4*)nidx)[i] = ksrc[i];
    }
    __syncthreads();

    int t = tid & (GPR - 1);
    int r0 = tid / GPR;
    int col8 = t * 8;
    float sc8[8], sh8[8];
    #pragma unroll
    for (int j = 0; j < 8; j++) { sc8[j] = scsh[col8 + j]; sh8[j] = scsh[CIN + col8 + j]; }

    int ra = node0 + r0;
    int rb = node0 + r0 + R;
    const unsigned short* abase = ain + (size_t)batch * NPTS * CIN;

    float acca[8], accb[8];
    {
        uint4 va = *(const uint4*)(ain + (size_t)ra * CIN + col8);
        uint4 vb = *(const uint4*)(ain + (size_t)rb * CIN + col8);
        unsigned wa[4] = {va.x, va.y, va.z, va.w};
        unsigned wb[4] = {vb.x, vb.y, vb.z, vb.w};
        #pragma unroll
        for (int j = 0; j < 4; j++) {
            acca[2*j]   = fmaxf(hu2f((unsigned short)(wa[j] & 0xFFFF)) * sc8[2*j]   + sh8[2*j],   0.f);
            acca[2*j+1] = fmaxf(hu2f((unsigned short)(wa[j] >> 16))    * sc8[2*j+1] + sh8[2*j+1], 0.f);
            accb[2*j]   = fmaxf(hu2f((unsigned short)(wb[j] & 0xFFFF)) * sc8[2*j]   + sh8[2*j],   0.f);
            accb[2*j+1] = fmaxf(hu2f((unsigned short)(wb[j] >> 16))    * sc8[2*j+1] + sh8[2*j+1], 0.f);
        }
    }
    #pragma unroll
    for (int jn = 0; jn < KNN; jn++) {
        int sa = nidx[r0 * KNN + jn];
        int sb = nidx[(r0 + R) * KNN + jn];
        uint4 va = *(const uint4*)(abase + (size_t)sa * CIN + col8);
        uint4 vb = *(const uint4*)(abase + (size_t)sb * CIN + col8);
        unsigned wa[4] = {va.x, va.y, va.z, va.w};
        unsigned wb[4] = {vb.x, vb.y, vb.z, vb.w};
        #pragma unroll
        for (int j = 0; j < 4; j++) {
            acca[2*j]   += fmaxf(hu2f((unsigned short)(wa[j] & 0xFFFF)) * sc8[2*j]   + sh8[2*j],   0.f);
            acca[2*j+1] += fmaxf(hu2f((unsigned short)(wa[j] >> 16))    * sc8[2*j+1] + sh8[2*j+1], 0.f);
            accb[2*j]   += fmaxf(hu2f((unsigned short)(wb[j] & 0xFFFF)) * sc8[2*j]   + sh8[2*j],   0.f);
            accb[2*j+1] += fmaxf(hu2f((unsigned short)(wb[j] >> 16))    * sc8[2*j+1] + sh8[2*j+1], 0.f);
        }
    }
    uint4 oa, ob;
    oa.x = f2hu(acca[0]) | ((unsigned)f2hu(acca[1]) << 16);
    oa.y = f2hu(acca[2]) | ((unsigned)f2hu(acca[3]) << 16);
    oa.z = f2hu(acca[4]) | ((unsigned)f2hu(acca[5]) << 16);
    oa.w = f2hu(acca[6]) | ((unsigned)f2hu(acca[7]) << 16);
    ob.x = f2hu(accb[0]) | ((unsigned)f2hu(accb[1]) << 16);
    ob.y = f2hu(accb[2]) | ((unsigned)f2hu(accb[3]) << 16);
    ob.z = f2hu(accb[4]) | ((unsigned)f2hu(accb[5]) << 16);
    ob.w = f2hu(accb[6]) | ((unsigned)f2hu(accb[7]) << 16);
    *(uint4*)(S + (size_t)ra * CIN + col8) = oa;
    *(uint4*)(S + (size_t)rb * CIN + col8) = ob;
}

// ---------------------------------------------------------------------------
// k_gemm<CIN,COUT,NSPLIT,STORE,FUSE>: LDS-staged-A GEMM, register-resident W.
// FUSE: last block computes scshOut (bncoef) from the 64 stat partitions.
// ---------------------------------------------------------------------------
template <int CIN, int COUT, int NSPLIT, bool STORE, bool FUSE>
__global__ __launch_bounds__(256) void k_gemm(
    const unsigned short* __restrict__ S, const unsigned short* __restrict__ WT,
    const float* __restrict__ bias,
    unsigned short* __restrict__ aout, float* __restrict__ statsOut, unsigned* __restrict__ mm,
    const float* __restrict__ gamma, const float* __restrict__ beta,
    float* __restrict__ scshOut, unsigned* __restrict__ counter)
{
    constexpr int KC = CIN / 32;
    constexpr int MT = 128;
    constexpr int SST = CIN + 8;
    constexpr int CPB = COUT / NSPLIT;
    constexpr int CPW = CPB / 4;
    constexpr int NT = CPW / 16;

    __shared__ alignas(16) unsigned short sA[MT * SST];

    int tid = threadIdx.x;
    int blk = blockIdx.x;
    int xcd = blk & 7;
    int rest = blk >> 3;
    int nq = rest % NSPLIT;
    int mseq = rest / NSPLIT;
    int phase = mseq >> 6;
    int within = mseq & 63;
    int batch = xcd + 8 * phase;
    int node0 = batch * NPTS + within * MT;
    int cbase = nq * CPB;
    int pout = batch * 4 + (within >> 4);

    {
        constexpr int TOT = MT * CIN / 8;
        const uint4* src = (const uint4*)(S + (size_t)node0 * CIN);
        #pragma unroll
        for (int i = tid; i < TOT; i += 256) {
            int row = i / (CIN / 8);
            int col8 = (i % (CIN / 8)) * 8;
            *(uint4*)&sA[row * SST + col8] = src[i];
        }
    }
    __syncthreads();

    int lane = tid & 63, wv = tid >> 6;
    int n15 = lane & 15, qd = lane >> 4;
    int c0 = cbase + wv * CPW;

    f16x8 wf[KC][NT];
    float bz[NT];
    #pragma unroll
    for (int nt = 0; nt < NT; nt++) {
        int c = c0 + nt * 16 + n15;
        bz[nt] = bias[c];
        #pragma unroll
        for (int kc = 0; kc < KC; kc++)
            wf[kc][nt] = *(const f16x8*)(WT + (size_t)c * CIN + kc * 32 + qd * 8);
    }
    float sacc[NT], qacc[NT], mxa[NT], mna[NT];
    #pragma unroll
    for (int nt = 0; nt < NT; nt++) {
        sacc[nt] = 0.f; qacc[nt] = 0.f; mxa[nt] = -3.4e38f; mna[nt] = 3.4e38f;
    }

    #pragma unroll
    for (int mt = 0; mt < MT / 16; mt++) {
        f16x8 af[KC];
        #pragma unroll
        for (int kc = 0; kc < KC; kc++)
            af[kc] = *(const f16x8*)&sA[(mt * 16 + n15) * SST + kc * 32 + qd * 8];

        f32x4 acc[NT];
        #pragma unroll
        for (int nt = 0; nt < NT; nt++) acc[nt] = (f32x4)(0.f);
        #pragma unroll
        for (int kc = 0; kc < KC; kc++)
            #pragma unroll
            for (int nt = 0; nt < NT; nt++)
                acc[nt] = __builtin_amdgcn_mfma_f32_16x16x32_f16(af[kc], wf[kc][nt], acc[nt], 0, 0, 0);

        #pragma unroll
        for (int nt = 0; nt < NT; nt++) {
            int c = c0 + nt * 16 + n15;
            #pragma unroll
            for (int r = 0; r < 4; r++) {
                float a = acc[nt][r];
                sacc[nt] += a;
                qacc[nt] = fmaf(a, a, qacc[nt]);
                if (!STORE) {
                    mxa[nt] = fmaxf(mxa[nt], a);
                    mna[nt] = fminf(mna[nt], a);
                }
                if (STORE) {
                    float v = a * DEGINV + bz[nt];
                    int node = node0 + mt * 16 + qd * 4 + r;
                    aout[(size_t)node * COUT + c] = f2hu(v);
                }
            }
        }
    }

    #pragma unroll
    for (int nt = 0; nt < NT; nt++) {
        int c = c0 + nt * 16 + n15;
        float S_ = sacc[nt], Q_ = qacc[nt];
        S_ += __shfl_xor(S_, 16); S_ += __shfl_xor(S_, 32);
        Q_ += __shfl_xor(Q_, 16); Q_ += __shfl_xor(Q_, 32);
        if (!STORE) {
            float mx = mxa[nt], mn = mna[nt];
            mx = fmaxf(mx, __shfl_xor(mx, 16)); mx = fmaxf(mx, __shfl_xor(mx, 32));
            mn = fminf(mn, __shfl_xor(mn, 16)); mn = fminf(mn, __shfl_xor(mn, 32));
            if (lane < 16) {
                atomicMax(mm + batch * COUT + c, fenc(mx * DEGINV + bz[nt]));
                atomicMin(mm + BATCH * COUT + batch * COUT + c, fenc(mn * DEGINV + bz[nt]));
            }
        }
        if (lane < 16) {
            float b = bz[nt];
            float s = DEGINV * S_ + (float)MT * b;
            float q = DEGINV * DEGINV * Q_ + 2.f * DEGINV * b * S_ + (float)MT * b * b;
            atomicAdd(statsOut + (size_t)pout * 2 * COUT + c, s);
            atomicAdd(statsOut + (size_t)pout * 2 * COUT + COUT + c, q);
        }
    }

    if (FUSE) {
        __syncthreads();                  // drain all waves' atomics
        __shared__ bool last;
        if (tid == 0) {
            __threadfence();
            last = (atomicAdd(counter, 1u) == (unsigned)gridDim.x - 1u);
        }
        __syncthreads();
        if (last && tid < COUT) {
            float ss = 0.f, qq = 0.f;
            for (int p = 0; p < 64; p++) {
                ss += atomicAdd(statsOut + (size_t)p * 2 * COUT + tid, 0.f);
                qq += atomicAdd(statsOut + (size_t)p * 2 * COUT + COUT + tid, 0.f);
            }
            float m = ss * (1.f / NROWS);
            float var = fmaxf(qq * (1.f / NROWS) - m * m, 0.f);
            float sc = gamma[tid] * rsqrtf(var + EPSBN);
            scshOut[tid] = sc;
            scshOut[COUT + tid] = beta[tid] - m * sc;
        }
    }
}

// ---------------------------------------------------------------------------
// k_e2: pooled codeword (computed in-block) + Linear(512,512) -> a4, stats4.
// 128 blocks = 16 batches x 8 channel-groups of 64.
// ---------------------------------------------------------------------------
__global__ __launch_bounds__(256) void k_e2(
    const float* __restrict__ stats3p, const unsigned* __restrict__ mm,
    const float* __restrict__ g2g, const float* __restrict__ g2be,
    const float* __restrict__ e2w, const float* __restrict__ e2b,
    float* __restrict__ a4, float* __restrict__ stats4)
{
    __shared__ float pooled[512];
    __shared__ float red[4][64];
    int blk = blockIdx.x;
    int b = blk >> 3, cg = blk & 7;
    int tid = threadIdx.x;
    for (int c = tid; c < 512; c += 256) {
        float s = 0.f, qq = 0.f;
        for (int p = 0; p < 64; p++) {
            s += stats3p[p * 1024 + c];
            qq += stats3p[p * 1024 + 512 + c];
        }
        float m = s * (1.f / NROWS);
        float var = fmaxf(qq * (1.f / NROWS) - m * m, 0.f);
        float sc = g2g[c] * rsqrtf(var + EPSBN);
        float sh = g2be[c] - m * sc;
        float amax = fdec(mm[b * 512 + c]);
        float amin = fdec(mm[8192 + b * 512 + c]);
        // max over nodes of relu(bn(a3)): monotone affine -> at an extreme
        pooled[c] = fmaxf(fmaxf(sc * amax + sh, 0.f), fmaxf(sc * amin + sh, 0.f));
    }
    __syncthreads();

    int c = cg * 64 + (tid & 63);
    int fg = tid >> 6;
    float acc = 0.f;
    #pragma unroll 4
    for (int f = fg * 128; f < fg * 128 + 128; f++)
        acc += pooled[f] * e2w[(size_t)f * 512 + c];
    red[fg][tid & 63] = acc;
    __syncthreads();
    if (tid < 64) {
        int cc = cg * 64 + tid;
        float v = red[0][tid] + red[1][tid] + red[2][tid] + red[3][tid] + e2b[cc];
        a4[b * 512 + cc] = v;
        atomicAdd(stats4 + cc, v);
        atomicAdd(stats4 + 512 + cc, v * v);
    }
}

// ---------------------------------------------------------------------------
// k_code: BN4+relu -> code; c1 = code@d1_w[:512], c2 = code@d2_w[:512]
// ---------------------------------------------------------------------------
__global__ __launch_bounds__(256) void k_code(
    const float* __restrict__ a4, const float* __restrict__ stats4,
    const float* __restrict__ e2g, const float* __restrict__ e2be,
    const float* __restrict__ d1w, const float* __restrict__ d2w,
    const float* __restrict__ gn,
    float* __restrict__ c1, float* __restrict__ c2,
    float* __restrict__ c1stats, float* __restrict__ gnstats)
{
    int b = blockIdx.x, tid = threadIdx.x;
    int lane = tid & 63, wv = tid >> 6;
    float p1[3] = {0, 0, 0}, p2[3] = {0, 0, 0};
    for (int c = tid; c < 512; c += 256) {
        float s = stats4[c], qq = stats4[512 + c];
        float m = s * (1.f / 16.f);
        float var = fmaxf(qq * (1.f / 16.f) - m * m, 0.f);
        float sc = e2g[c] * rsqrtf(var + EPSBN);
        float sh = e2be[c] - m * sc;
        float cv = fmaxf(sc * a4[b * 512 + c] + sh, 0.f);
        #pragma unroll
        for (int j = 0; j < 3; j++) {
            p1[j] += cv * d1w[c * 3 + j];
            p2[j] += cv * d2w[c * 3 + j];
        }
    }
    __shared__ float red[4][6];
    #pragma unroll
    for (int j = 0; j < 3; j++)
        for (int off = 32; off; off >>= 1) {
            p1[j] += __shfl_xor(p1[j], off);
            p2[j] += __shfl_xor(p2[j], off);
        }
    if (lane == 0) {
        #pragma unroll
        for (int j = 0; j < 3; j++) { red[wv][j] = p1[j]; red[wv][3 + j] = p2[j]; }
    }
    __syncthreads();
    if (tid < 3) {
        float v = red[0][tid] + red[1][tid] + red[2][tid] + red[3][tid];
        c1[b * 3 + tid] = v;
        atomicAdd(c1stats + tid, v);
        atomicAdd(c1stats + 3 + tid, v * v);
    } else if (tid < 6) {
        int j = tid - 3;
        float v = red[0][tid] + red[1][tid] + red[2][tid] + red[3][tid];
        c2[b * 3 + j] = v;
    }
    if (blockIdx.x == 0) {
        float g1[3] = {0, 0, 0}, g2s[3] = {0, 0, 0};
        for (int n = tid; n < NPTS; n += 256) {
            #pragma unroll
            for (int j = 0; j < 3; j++) {
                float g = gn[n * 3 + j];
                g1[j] += g; g2s[j] += g * g;
            }
        }
        #pragma unroll
        for (int j = 0; j < 3; j++)
            for (int off = 32; off; off >>= 1) {
                g1[j] += __shfl_xor(g1[j], off);
                g2s[j] += __shfl_xor(g2s[j], off);
            }
        __shared__ float redg[4][6];
        if (lane == 0) {
            #pragma unroll
            for (int j = 0; j < 3; j++) { redg[wv][j] = g1[j]; redg[wv][3 + j] = g2s[j]; }
        }
        __syncthreads();
        if (tid < 6)
            gnstats[tid] = redg[0][tid] + redg[1][tid] + redg[2][tid] + redg[3][tid];
    }
}

// ---------------------------------------------------------------------------
__device__ __forceinline__ void d1_coefs(
    const float* c1stats, const float* gnstats,
    const float* d1g, const float* d1be, float* scd, float* shd)
{
    #pragma unroll
    for (int j = 0; j < 3; j++) {
        float mc = c1stats[j] * (1.f / 16.f), qc = c1stats[3 + j] * (1.f / 16.f);
        float mg = gnstats[j] * (1.f / 8192.f), qg = gnstats[3 + j] * (1.f / 8192.f);
        float m = mc + mg;
        float var = fmaxf((qc - mc * mc) + (qg - mg * mg), 0.f);
        float sc = d1g[j] * rsqrtf(var + EPSBN);
        scd[j] = sc;
        shd[j] = d1be[j] - m * sc;
    }
}

// ---------------------------------------------------------------------------
__global__ __launch_bounds__(256) void k_d2stats(
    const float* __restrict__ c1, const float* __restrict__ c2, const float* __restrict__ gn,
    const float* __restrict__ c1stats, const float* __restrict__ gnstats,
    const float* __restrict__ d1g, const float* __restrict__ d1be,
    const float* __restrict__ d2w, const float* __restrict__ d2b,
    float* __restrict__ statsd2)
{
    int gid = blockIdx.x * 256 + threadIdx.x;
    int b = gid >> 13, n = gid & 8191;
    int lane = threadIdx.x & 63, wv = threadIdx.x >> 6;
    float scd[3], shd[3];
    d1_coefs(c1stats, gnstats, d1g, d1be, scd, shd);
    float z3[3];
    #pragma unroll
    for (int j = 0; j < 3; j++)
        z3[j] = fmaxf(scd[j] * (c1[b * 3 + j] + gn[n * 3 + j]) + shd[j], 0.f);
    float vals[6];
    #pragma unroll
    for (int u = 0; u < 3; u++) {
        float a = c2[b * 3 + u]
                + z3[0] * d2w[512 * 3 + u]
                + z3[1] * d2w[513 * 3 + u]
                + z3[2] * d2w[514 * 3 + u]
                + d2b[u];
        vals[u] = a; vals[3 + u] = a * a;
    }
    #pragma unroll
    for (int j = 0; j < 6; j++)
        for (int off = 32; off; off >>= 1) vals[j] += __shfl_xor(vals[j], off);
    __shared__ float red[4][6];
    if (lane == 0) {
        #pragma unroll
        for (int j = 0; j < 6; j++) red[wv][j] = vals[j];
    }
    __syncthreads();
    if (threadIdx.x < 6)
        atomicAdd(statsd2 + threadIdx.x,
                  red[0][threadIdx.x] + red[1][threadIdx.x] + red[2][threadIdx.x] + red[3][threadIdx.x]);
}

// ---------------------------------------------------------------------------
__global__ __launch_bounds__(256) void k_out(
    const float* __restrict__ c1, const float* __restrict__ c2, const float* __restrict__ gn,
    const float* __restrict__ c1stats, const float* __restrict__ gnstats,
    const float* __restrict__ statsd2,
    const float* __restrict__ d1g, const float* __restrict__ d1be,
    const float* __restrict__ d2w, const float* __restrict__ d2b,
    const float* __restrict__ d2g, const float* __restrict__ d2be,
    float* __restrict__ out)
{
    int gid = blockIdx.x * 256 + threadIdx.x;
    int b = gid >> 13, n = gid & 8191;
    float scd[3], shd[3];
    d1_coefs(c1stats, gnstats, d1g, d1be, scd, shd);
    float z3[3];
    #pragma unroll
    for (int j = 0; j < 3; j++)
        z3[j] = fmaxf(scd[j] * (c1[b * 3 + j] + gn[n * 3 + j]) + shd[j], 0.f);
    #pragma unroll
    for (int u = 0; u < 3; u++) {
        float a = c2[b * 3 + u]
                + z3[0] * d2w[512 * 3 + u]
                + z3[1] * d2w[513 * 3 + u]
                + z3[2] * d2w[514 * 3 + u]
                + d2b[u];
        float m2 = statsd2[u] * (1.f / (float)NROWS);
        float v2 = fmaxf(statsd2[3 + u] * (1.f / (float)NROWS) - m2 * m2, 0.f);
        float sc = d2g[u] * rsqrtf(v2 + EPSBN);
        float sh = d2be[u] - m2 * sc;
        out[(size_t)gid * 3 + u] = fmaxf(sc * a + sh, 0.f);
    }
}

// ---------------------------------------------------------------------------
extern "C" void kernel_launch(void* const* d_in, const int* in_sizes, int n_in,
                              void* d_out, int out_size, void* d_ws, size_t ws_size,
                              hipStream_t stream)
{
    (void)in_sizes; (void)n_in; (void)out_size; (void)ws_size;
    const float* data = (const float*)d_in[0];
    const int*   knn  = (const int*)d_in[1];
    const float* e1w = (const float*)d_in[2],  *e1b = (const float*)d_in[3];
    const float* e1g = (const float*)d_in[4],  *e1be = (const float*)d_in[5];
    const float* gc1w = (const float*)d_in[6], *gc1b = (const float*)d_in[7];
    const float* g1g = (const float*)d_in[8],  *g1be = (const float*)d_in[9];
    const float* gc2w = (const float*)d_in[10], *gc2b = (const float*)d_in[11];
    const float* g2g = (const float*)d_in[12], *g2be = (const float*)d_in[13];
    const float* e2w = (const float*)d_in[14], *e2b = (const float*)d_in[15];
    const float* e2g = (const float*)d_in[16], *e2be = (const float*)d_in[17];
    const float* d1w = (const float*)d_in[18], *d1b = (const float*)d_in[19];
    const float* d1g = (const float*)d_in[20], *d1be = (const float*)d_in[21];
    const float* d2w = (const float*)d_in[22], *d2b = (const float*)d_in[23];
    const float* d2g = (const float*)d_in[24], *d2be = (const float*)d_in[25];

    char* p = (char*)d_ws;
    auto alloc = [&](size_t bytes) -> void* {
        void* r = (void*)p;
        p += (bytes + 255) & ~(size_t)255;
        return r;
    };
    unsigned short* a1  = (unsigned short*)alloc((size_t)NROWS * 64 * 2);  // 16.8 MB fp16
    unsigned short* a2h = (unsigned short*)alloc((size_t)NROWS * 128 * 2); // 33.5 MB fp16
    unsigned short* s1  = (unsigned short*)alloc((size_t)NROWS * 64 * 2);  // 16.8 MB fp16
    unsigned short* s2  = (unsigned short*)alloc((size_t)NROWS * 128 * 2); // 33.5 MB fp16
    float4* data4 = (float4*)alloc((size_t)NROWS * 16);                    // 2 MB
    unsigned short* W1T = (unsigned short*)alloc(8192 * 2);
    unsigned short* W2T = (unsigned short*)alloc(65536 * 2);
    float* statszone = (float*)alloc(SZ_TOT * 4);
    float* stats1  = statszone + SZ_S1;
    float* stats2p = statszone + SZ_S2P;
    float* stats3p = statszone + SZ_S3P;
    float* stats4  = statszone + SZ_S4;
    float* c1stats = statszone + SZ_C1;
    float* gnstats = statszone + SZ_GN;
    float* statsd2 = statszone + SZ_D2;
    float* scsh1   = statszone + SZ_SCSH1;
    float* scsh2   = statszone + SZ_SCSH2;
    unsigned* mm = (unsigned*)alloc(16386 * 4);   // +2 counters
    float* a4 = (float*)alloc(16 * 512 * 4);
    float* c1 = (float*)alloc(64 * 4);
    float* c2 = (float*)alloc(64 * 4);
    float* gn = (float*)alloc(8192 * 3 * 4);

    k_prep<<<128, 256, 0, stream>>>(data, gc1w, gc2w, d1w, d1b, W1T, W2T, gn,
                                    statszone, mm, data4);
    k_cov_e1<<<512, 256, 0, stream>>>(data4, knn, e1w, e1b, a1);
    k_reduce_a1<<<256, 256, 0, stream>>>(a1, stats1, e1g, e1be, scsh1, mm + 16384);
    k_gather16<64><<<NROWS / 64, 256, 0, stream>>>(a1, knn, scsh1, s1);
    k_gemm<64, 128, 1, true, true><<<1024, 256, 0, stream>>>(
        s1, W1T, gc1b, a2h, stats2p, nullptr, g1g, g1be, scsh2, mm + 16385);
    k_gather16<128><<<NROWS / 32, 256, 0, stream>>>(a2h, knn, scsh2, s2);
    k_gemm<128, 512, 4, false, false><<<4096, 256, 0, stream>>>(
        s2, W2T, gc2b, nullptr, stats3p, mm, nullptr, nullptr, nullptr, nullptr);
    k_e2<<<128, 256, 0, stream>>>(stats3p, mm, g2g, g2be, e2w, e2b, a4, stats4);
    k_code<<<16, 256, 0, stream>>>(a4, stats4, e2g, e2be, d1w, d2w, gn, c1, c2, c1stats, gnstats);
    k_d2stats<<<512, 256, 0, stream>>>(c1, c2, gn, c1stats, gnstats, d1g, d1be, d2w, d2b, statsd2);
    k_out<<<512, 256, 0, stream>>>(c1, c2, gn, c1stats, gnstats, statsd2,
                                   d1g, d1be, d2w, d2b, d2g, d2be, (float*)d_out);
}

// Round 16
// 329.557 us; speedup vs baseline: 1.1316x; 1.1316x over previous
//
#include <hip/hip_runtime.h>
#include <hip/hip_fp16.h>
#include <stdint.h>

#define BATCH 16
#define NPTS  8192
#define KNN   16
#define NROWS (BATCH*NPTS)     // 131072
#define EPSBN 1e-5f
#define DEGINV (1.0f/17.0f)

typedef _Float16 f16x8 __attribute__((ext_vector_type(8)));
typedef float    f32x4 __attribute__((ext_vector_type(4)));

__device__ __forceinline__ unsigned short f2hu(float f) {
    union { _Float16 h; unsigned short u; } cv;
    cv.h = (_Float16)f;
    return cv.u;
}
__device__ __forceinline__ float hu2f(unsigned short u) {
    union { unsigned short u; _Float16 h; } cv;
    cv.u = u;
    return (float)cv.h;
}
// order-preserving float <-> uint encoding (for atomic min/max)
__device__ __forceinline__ unsigned fenc(float f) {
    unsigned u = __float_as_uint(f);
    return (int)u >= 0 ? (u | 0x80000000u) : ~u;
}
__device__ __forceinline__ float fdec(unsigned k) {
    return (k & 0x80000000u) ? __uint_as_float(k & 0x7FFFFFFFu) : __uint_as_float(~k);
}

// stats zone layout (floats):
#define SZ_S1    0        // stats1: 64 sum + 64 sumsq
#define SZ_S2P   128      // stats2p: 64 x (128+128)
#define SZ_S3P   16512    // stats3p: 64 x (512+512)
#define SZ_S4    82048    // stats4: 512+512
#define SZ_C1    83072
#define SZ_GN    83080
#define SZ_D2    83088
#define SZ_SCSH1 83096    // 2*64
#define SZ_SCSH2 83224    // 2*128
#define SZ_TOT   83480

// ---------------------------------------------------------------------------
// k_prep: zero stats, init min/max sentinels, fp16 W^T copies, grid feats,
// xyz -> float4-padded data4
// ---------------------------------------------------------------------------
__global__ __launch_bounds__(256) void k_prep(
    const float* __restrict__ data, const float* __restrict__ gc1w,
    const float* __restrict__ gc2w,
    const float* __restrict__ d1w, const float* __restrict__ d1b,
    unsigned short* __restrict__ W1T, unsigned short* __restrict__ W2T,
    float* __restrict__ gn, float* __restrict__ statszone, unsigned* __restrict__ mm,
    float4* __restrict__ data4)
{
    int t = blockIdx.x * 256 + threadIdx.x;
    int NT_ = gridDim.x * 256;
    for (int i = t; i < 65536; i += NT_) {          // W2T[c][k] = gc2_w[k][c]
        int c = i >> 7, k = i & 127;
        W2T[i] = f2hu(gc2w[k * 512 + c]);
    }
    for (int i = t; i < 8192; i += NT_) {           // W1T[c][k] = gc1_w[k][c]
        int c = i >> 6, k = i & 63;
        W1T[i] = f2hu(gc1w[k * 128 + c]);
    }
    for (int i = t; i < SZ_TOT; i += NT_) statszone[i] = 0.f;
    for (int i = t; i < 8192; i += NT_) mm[i] = 0u;                 // max enc
    for (int i = t; i < 8192; i += NT_) mm[8192 + i] = 0xFFFFFFFFu; // min enc
    for (int i = t; i < NROWS; i += NT_) {
        float4 v;
        v.x = data[(size_t)i * 3 + 0];
        v.y = data[(size_t)i * 3 + 1];
        v.z = data[(size_t)i * 3 + 2];
        v.w = 0.f;
        data4[i] = v;
    }
    for (int n = t; n < 8192; n += NT_) {
        int ix = n / 65, iy = n % 65;
        float gx = 1.f + ix * (119.f / 128.f);
        float gy = 1.f + iy * (59.f / 64.f);
        #pragma unroll
        for (int j = 0; j < 3; j++)
            gn[n * 3 + j] = gx * d1w[512 * 3 + j] + gy * d1w[513 * 3 + j] + d1b[j];
    }
}

// ---------------------------------------------------------------------------
// k_cov_e1: covariance features + Linear(12,64) -> a1 [131072][64] fp16
// float4-padded point loads: 1 load per neighbor (was 3 scalars)
// ---------------------------------------------------------------------------
__global__ __launch_bounds__(256) void k_cov_e1(
    const float4* __restrict__ data4, const int* __restrict__ knn,
    const float* __restrict__ e1w, const float* __restrict__ e1b,
    unsigned short* __restrict__ a1)
{
    __shared__ float w[12 * 64];
    __shared__ float bias[64];
    int tid = threadIdx.x;
    for (int i = tid; i < 768; i += 256) w[i] = e1w[i];
    if (tid < 64) bias[tid] = e1b[tid];
    __syncthreads();

    int gid = blockIdx.x * 256 + tid;
    int b = gid >> 13;
    const float4* db4 = data4 + (size_t)b * NPTS;
    const int4* k4 = (const int4*)knn + gid * 4;

    float sx = 0, sy = 0, sz = 0, Sxx = 0, Sxy = 0, Sxz = 0, Syy = 0, Syz = 0, Szz = 0;
    #pragma unroll
    for (int jj = 0; jj < 4; jj++) {
        int4 q = k4[jj];
        int id[4] = {q.x, q.y, q.z, q.w};
        #pragma unroll
        for (int u = 0; u < 4; u++) {
            float4 p = db4[id[u]];
            float x = p.x, y = p.y, z = p.z;
            sx += x; sy += y; sz += z;
            Sxx += x * x; Sxy += x * y; Sxz += x * z;
            Syy += y * y; Syz += y * z; Szz += z * z;
        }
    }
    float mx = sx * (1.f / 16.f), my = sy * (1.f / 16.f), mz = sz * (1.f / 16.f);
    const float inv15 = 1.f / 15.f;
    float4 self = data4[gid];
    float x12[12];
    x12[0] = self.x;
    x12[1] = self.y;
    x12[2] = self.z;
    x12[3] = (Sxx - 16.f * mx * mx) * inv15;
    x12[4] = (Sxy - 16.f * mx * my) * inv15;
    x12[5] = (Sxz - 16.f * mx * mz) * inv15;
    x12[6] = x12[4];
    x12[7] = (Syy - 16.f * my * my) * inv15;
    x12[8] = (Syz - 16.f * my * mz) * inv15;
    x12[9] = x12[5];
    x12[10] = x12[8];
    x12[11] = (Szz - 16.f * mz * mz) * inv15;

    unsigned short* arow = a1 + (size_t)gid * 64;
    for (int c0 = 0; c0 < 64; c0 += 8) {
        float v8[8];
        #pragma unroll
        for (int u = 0; u < 8; u++) {
            int c = c0 + u;
            float acc = bias[c];
            #pragma unroll
            for (int i = 0; i < 12; i++) acc += x12[i] * w[i * 64 + c];
            v8[u] = acc;
        }
        uint4 o;
        o.x = f2hu(v8[0]) | ((unsigned)f2hu(v8[1]) << 16);
        o.y = f2hu(v8[2]) | ((unsigned)f2hu(v8[3]) << 16);
        o.z = f2hu(v8[4]) | ((unsigned)f2hu(v8[5]) << 16);
        o.w = f2hu(v8[6]) | ((unsigned)f2hu(v8[7]) << 16);
        *(uint4*)(arow + c0) = o;
    }
}

// ---------------------------------------------------------------------------
// k_reduce_a1: per-channel sum/sumsq of fp16 a1 (C=64) -> stats1
// ---------------------------------------------------------------------------
__global__ __launch_bounds__(256) void k_reduce_a1(
    const unsigned short* __restrict__ a1, float* __restrict__ stats1)
{
    int tid = threadIdx.x;
    int c = tid & 63, rq = tid >> 6;
    float s = 0.f, q = 0.f;
    for (int row = blockIdx.x * 4 + rq; row < NROWS; row += gridDim.x * 4) {
        float v = hu2f(a1[(size_t)row * 64 + c]);
        s += v; q += v * v;
    }
    __shared__ float red[2][256];
    red[0][tid] = s; red[1][tid] = q;
    __syncthreads();
    if (tid < 64) {
        s = red[0][tid] + red[0][tid + 64] + red[0][tid + 128] + red[0][tid + 192];
        q = red[1][tid] + red[1][tid + 64] + red[1][tid + 128] + red[1][tid + 192];
        atomicAdd(stats1 + tid, s);
        atomicAdd(stats1 + 64 + tid, q);
    }
}

// ---------------------------------------------------------------------------
// k_bncoef<C,NPARTS>: collapse partitioned stats -> (sc, sh) coef arrays
// ---------------------------------------------------------------------------
template <int C, int NPARTS>
__global__ __launch_bounds__(256) void k_bncoef(
    const float* __restrict__ statsIn,
    const float* __restrict__ gamma, const float* __restrict__ beta,
    float* __restrict__ scsh)
{
    int ch = threadIdx.x;
    if (ch < C) {
        float s = 0.f, q = 0.f;
        for (int p = 0; p < NPARTS; p++) {
            s += statsIn[p * 2 * C + ch];
            q += statsIn[p * 2 * C + C + ch];
        }
        float m = s * (1.f / NROWS);
        float var = fmaxf(q * (1.f / NROWS) - m * m, 0.f);
        float sc = gamma[ch] * rsqrtf(var + EPSBN);
        scsh[ch] = sc;
        scsh[C + ch] = beta[ch] - m * sc;
    }
}

// ---------------------------------------------------------------------------
// k_gather16: s[row] = bn_relu(a[row]) + sum_j bn_relu(a[knn_j]) -> fp16
// TWO rows per thread (independent chains, 34 x 16-B loads in flight).
// ---------------------------------------------------------------------------
template <int CIN>
__global__ __launch_bounds__(256) void k_gather16(
    const unsigned short* __restrict__ ain, const int* __restrict__ knn,
    const float* __restrict__ scsh, unsigned short* __restrict__ S)
{
    constexpr int GPR = CIN / 8;            // threads per row
    constexpr int R = 256 / GPR;            // rows per pass
    constexpr int R2 = 2 * R;               // rows per block
    constexpr int BPB = NPTS / R2;          // blocks per batch

    __shared__ int nidx[R2 * KNN];

    int tid = threadIdx.x;
    int blk = blockIdx.x;
    int xcd = blk & 7;
    int idx = blk >> 3;
    int batch = xcd + 8 * (idx / BPB);
    int within = idx % BPB;
    int node0 = batch * NPTS + within * R2;

    {
        const int4* ksrc = (const int4*)(knn + (size_t)node0 * KNN);
        for (int i = tid; i < R2 * 4; i += 256) ((int4*)nidx)[i] = ksrc[i];
    }
    __syncthreads();

    int t = tid & (GPR - 1);
    int r0 = tid / GPR;                     // [0,R)
    int col8 = t * 8;
    float sc8[8], sh8[8];
    #pragma unroll
    for (int j = 0; j < 8; j++) { sc8[j] = scsh[col8 + j]; sh8[j] = scsh[CIN + col8 + j]; }

    int ra = node0 + r0;
    int rb = node0 + r0 + R;
    const unsigned short* abase = ain + (size_t)batch * NPTS * CIN;

    float acca[8], accb[8];
    {
        uint4 va = *(const uint4*)(ain + (size_t)ra * CIN + col8);
        uint4 vb = *(const uint4*)(ain + (size_t)rb * CIN + col8);
        unsigned wa[4] = {va.x, va.y, va.z, va.w};
        unsigned wb[4] = {vb.x, vb.y, vb.z, vb.w};
        #pragma unroll
        for (int j = 0; j < 4; j++) {
            acca[2*j]   = fmaxf(hu2f((unsigned short)(wa[j] & 0xFFFF)) * sc8[2*j]   + sh8[2*j],   0.f);
            acca[2*j+1] = fmaxf(hu2f((unsigned short)(wa[j] >> 16))    * sc8[2*j+1] + sh8[2*j+1], 0.f);
            accb[2*j]   = fmaxf(hu2f((unsigned short)(wb[j] & 0xFFFF)) * sc8[2*j]   + sh8[2*j],   0.f);
            accb[2*j+1] = fmaxf(hu2f((unsigned short)(wb[j] >> 16))    * sc8[2*j+1] + sh8[2*j+1], 0.f);
        }
    }
    #pragma unroll
    for (int jn = 0; jn < KNN; jn++) {
        int sa = nidx[r0 * KNN + jn];
        int sb = nidx[(r0 + R) * KNN + jn];
        uint4 va = *(const uint4*)(abase + (size_t)sa * CIN + col8);
        uint4 vb = *(const uint4*)(abase + (size_t)sb * CIN + col8);
        unsigned wa[4] = {va.x, va.y, va.z, va.w};
        unsigned wb[4] = {vb.x, vb.y, vb.z, vb.w};
        #pragma unroll
        for (int j = 0; j < 4; j++) {
            acca[2*j]   += fmaxf(hu2f((unsigned short)(wa[j] & 0xFFFF)) * sc8[2*j]   + sh8[2*j],   0.f);
            acca[2*j+1] += fmaxf(hu2f((unsigned short)(wa[j] >> 16))    * sc8[2*j+1] + sh8[2*j+1], 0.f);
            accb[2*j]   += fmaxf(hu2f((unsigned short)(wb[j] & 0xFFFF)) * sc8[2*j]   + sh8[2*j],   0.f);
            accb[2*j+1] += fmaxf(hu2f((unsigned short)(wb[j] >> 16))    * sc8[2*j+1] + sh8[2*j+1], 0.f);
        }
    }
    uint4 oa, ob;
    oa.x = f2hu(acca[0]) | ((unsigned)f2hu(acca[1]) << 16);
    oa.y = f2hu(acca[2]) | ((unsigned)f2hu(acca[3]) << 16);
    oa.z = f2hu(acca[4]) | ((unsigned)f2hu(acca[5]) << 16);
    oa.w = f2hu(acca[6]) | ((unsigned)f2hu(acca[7]) << 16);
    ob.x = f2hu(accb[0]) | ((unsigned)f2hu(accb[1]) << 16);
    ob.y = f2hu(accb[2]) | ((unsigned)f2hu(accb[3]) << 16);
    ob.z = f2hu(accb[4]) | ((unsigned)f2hu(accb[5]) << 16);
    ob.w = f2hu(accb[6]) | ((unsigned)f2hu(accb[7]) << 16);
    *(uint4*)(S + (size_t)ra * CIN + col8) = oa;
    *(uint4*)(S + (size_t)rb * CIN + col8) = ob;
}

// ---------------------------------------------------------------------------
// k_gemm<CIN,COUT,NSPLIT,STORE>: LDS-staged-A GEMM, small register-resident W.
// ---------------------------------------------------------------------------
template <int CIN, int COUT, int NSPLIT, bool STORE>
__global__ __launch_bounds__(256) void k_gemm(
    const unsigned short* __restrict__ S, const unsigned short* __restrict__ WT,
    const float* __restrict__ bias,
    unsigned short* __restrict__ aout, float* __restrict__ statsOut, unsigned* __restrict__ mm)
{
    constexpr int KC = CIN / 32;
    constexpr int MT = 128;
    constexpr int SST = CIN + 8;
    constexpr int CPB = COUT / NSPLIT;
    constexpr int CPW = CPB / 4;
    constexpr int NT = CPW / 16;

    __shared__ alignas(16) unsigned short sA[MT * SST];

    int tid = threadIdx.x;
    int blk = blockIdx.x;
    int xcd = blk & 7;
    int rest = blk >> 3;
    int nq = rest % NSPLIT;
    int mseq = rest / NSPLIT;
    int phase = mseq >> 6;
    int within = mseq & 63;
    int batch = xcd + 8 * phase;
    int node0 = batch * NPTS + within * MT;
    int cbase = nq * CPB;
    int pout = batch * 4 + (within >> 4);

    {
        constexpr int TOT = MT * CIN / 8;
        const uint4* src = (const uint4*)(S + (size_t)node0 * CIN);
        #pragma unroll
        for (int i = tid; i < TOT; i += 256) {
            int row = i / (CIN / 8);
            int col8 = (i % (CIN / 8)) * 8;
            *(uint4*)&sA[row * SST + col8] = src[i];
        }
    }
    __syncthreads();

    int lane = tid & 63, wv = tid >> 6;
    int n15 = lane & 15, qd = lane >> 4;
    int c0 = cbase + wv * CPW;

    f16x8 wf[KC][NT];
    float bz[NT];
    #pragma unroll
    for (int nt = 0; nt < NT; nt++) {
        int c = c0 + nt * 16 + n15;
        bz[nt] = bias[c];
        #pragma unroll
        for (int kc = 0; kc < KC; kc++)
            wf[kc][nt] = *(const f16x8*)(WT + (size_t)c * CIN + kc * 32 + qd * 8);
    }
    float sacc[NT], qacc[NT], mxa[NT], mna[NT];
    #pragma unroll
    for (int nt = 0; nt < NT; nt++) {
        sacc[nt] = 0.f; qacc[nt] = 0.f; mxa[nt] = -3.4e38f; mna[nt] = 3.4e38f;
    }

    #pragma unroll
    for (int mt = 0; mt < MT / 16; mt++) {
        f16x8 af[KC];
        #pragma unroll
        for (int kc = 0; kc < KC; kc++)
            af[kc] = *(const f16x8*)&sA[(mt * 16 + n15) * SST + kc * 32 + qd * 8];

        f32x4 acc[NT];
        #pragma unroll
        for (int nt = 0; nt < NT; nt++) acc[nt] = (f32x4)(0.f);
        #pragma unroll
        for (int kc = 0; kc < KC; kc++)
            #pragma unroll
            for (int nt = 0; nt < NT; nt++)
                acc[nt] = __builtin_amdgcn_mfma_f32_16x16x32_f16(af[kc], wf[kc][nt], acc[nt], 0, 0, 0);

        #pragma unroll
        for (int nt = 0; nt < NT; nt++) {
            int c = c0 + nt * 16 + n15;
            #pragma unroll
            for (int r = 0; r < 4; r++) {
                float a = acc[nt][r];
                sacc[nt] += a;
                qacc[nt] = fmaf(a, a, qacc[nt]);
                if (!STORE) {
                    mxa[nt] = fmaxf(mxa[nt], a);
                    mna[nt] = fminf(mna[nt], a);
                }
                if (STORE) {
                    float v = a * DEGINV + bz[nt];
                    int node = node0 + mt * 16 + qd * 4 + r;
                    aout[(size_t)node * COUT + c] = f2hu(v);
                }
            }
        }
    }

    #pragma unroll
    for (int nt = 0; nt < NT; nt++) {
        int c = c0 + nt * 16 + n15;
        float S_ = sacc[nt], Q_ = qacc[nt];
        S_ += __shfl_xor(S_, 16); S_ += __shfl_xor(S_, 32);
        Q_ += __shfl_xor(Q_, 16); Q_ += __shfl_xor(Q_, 32);
        if (!STORE) {
            float mx = mxa[nt], mn = mna[nt];
            mx = fmaxf(mx, __shfl_xor(mx, 16)); mx = fmaxf(mx, __shfl_xor(mx, 32));
            mn = fminf(mn, __shfl_xor(mn, 16)); mn = fminf(mn, __shfl_xor(mn, 32));
            if (lane < 16) {
                atomicMax(mm + batch * COUT + c, fenc(mx * DEGINV + bz[nt]));
                atomicMin(mm + BATCH * COUT + batch * COUT + c, fenc(mn * DEGINV + bz[nt]));
            }
        }
        if (lane < 16) {
            float b = bz[nt];
            float s = DEGINV * S_ + (float)MT * b;
            float q = DEGINV * DEGINV * Q_ + 2.f * DEGINV * b * S_ + (float)MT * b * b;
            atomicAdd(statsOut + (size_t)pout * 2 * COUT + c, s);
            atomicAdd(statsOut + (size_t)pout * 2 * COUT + COUT + c, q);
        }
    }
}

// ---------------------------------------------------------------------------
// k_e2: pooled codeword (computed in-block) + Linear(512,512) -> a4, stats4.
// 128 blocks = 16 batches x 8 channel-groups of 64.
// ---------------------------------------------------------------------------
__global__ __launch_bounds__(256) void k_e2(
    const float* __restrict__ stats3p, const unsigned* __restrict__ mm,
    const float* __restrict__ g2g, const float* __restrict__ g2be,
    const float* __restrict__ e2w, const float* __restrict__ e2b,
    float* __restrict__ a4, float* __restrict__ stats4)
{
    __shared__ float pooled[512];
    __shared__ float red[4][64];
    int blk = blockIdx.x;
    int b = blk >> 3, cg = blk & 7;
    int tid = threadIdx.x;
    for (int c = tid; c < 512; c += 256) {
        float s = 0.f, qq = 0.f;
        for (int p = 0; p < 64; p++) {
            s += stats3p[p * 1024 + c];
            qq += stats3p[p * 1024 + 512 + c];
        }
        float m = s * (1.f / NROWS);
        float var = fmaxf(qq * (1.f / NROWS) - m * m, 0.f);
        float sc = g2g[c] * rsqrtf(var + EPSBN);
        float sh = g2be[c] - m * sc;
        float amax = fdec(mm[b * 512 + c]);
        float amin = fdec(mm[8192 + b * 512 + c]);
        pooled[c] = fmaxf(fmaxf(sc * amax + sh, 0.f), fmaxf(sc * amin + sh, 0.f));
    }
    __syncthreads();

    int c = cg * 64 + (tid & 63);
    int fg = tid >> 6;
    float acc = 0.f;
    #pragma unroll 4
    for (int f = fg * 128; f < fg * 128 + 128; f++)
        acc += pooled[f] * e2w[(size_t)f * 512 + c];
    red[fg][tid & 63] = acc;
    __syncthreads();
    if (tid < 64) {
        int cc = cg * 64 + tid;
        float v = red[0][tid] + red[1][tid] + red[2][tid] + red[3][tid] + e2b[cc];
        a4[b * 512 + cc] = v;
        atomicAdd(stats4 + cc, v);
        atomicAdd(stats4 + 512 + cc, v * v);
    }
}

// ---------------------------------------------------------------------------
// k_code: BN4+relu -> code; c1 = code@d1_w[:512], c2 = code@d2_w[:512]
// ---------------------------------------------------------------------------
__global__ __launch_bounds__(256) void k_code(
    const float* __restrict__ a4, const float* __restrict__ stats4,
    const float* __restrict__ e2g, const float* __restrict__ e2be,
    const float* __restrict__ d1w, const float* __restrict__ d2w,
    const float* __restrict__ gn,
    float* __restrict__ c1, float* __restrict__ c2,
    float* __restrict__ c1stats, float* __restrict__ gnstats)
{
    int b = blockIdx.x, tid = threadIdx.x;
    int lane = tid & 63, wv = tid >> 6;
    float p1[3] = {0, 0, 0}, p2[3] = {0, 0, 0};
    for (int c = tid; c < 512; c += 256) {
        float s = stats4[c], qq = stats4[512 + c];
        float m = s * (1.f / 16.f);
        float var = fmaxf(qq * (1.f / 16.f) - m * m, 0.f);
        float sc = e2g[c] * rsqrtf(var + EPSBN);
        float sh = e2be[c] - m * sc;
        float cv = fmaxf(sc * a4[b * 512 + c] + sh, 0.f);
        #pragma unroll
        for (int j = 0; j < 3; j++) {
            p1[j] += cv * d1w[c * 3 + j];
            p2[j] += cv * d2w[c * 3 + j];
        }
    }
    __shared__ float red[4][6];
    #pragma unroll
    for (int j = 0; j < 3; j++)
        for (int off = 32; off; off >>= 1) {
            p1[j] += __shfl_xor(p1[j], off);
            p2[j] += __shfl_xor(p2[j], off);
        }
    if (lane == 0) {
        #pragma unroll
        for (int j = 0; j < 3; j++) { red[wv][j] = p1[j]; red[wv][3 + j] = p2[j]; }
    }
    __syncthreads();
    if (tid < 3) {
        float v = red[0][tid] + red[1][tid] + red[2][tid] + red[3][tid];
        c1[b * 3 + tid] = v;
        atomicAdd(c1stats + tid, v);
        atomicAdd(c1stats + 3 + tid, v * v);
    } else if (tid < 6) {
        int j = tid - 3;
        float v = red[0][tid] + red[1][tid] + red[2][tid] + red[3][tid];
        c2[b * 3 + j] = v;
    }
    if (blockIdx.x == 0) {
        float g1[3] = {0, 0, 0}, g2s[3] = {0, 0, 0};
        for (int n = tid; n < NPTS; n += 256) {
            #pragma unroll
            for (int j = 0; j < 3; j++) {
                float g = gn[n * 3 + j];
                g1[j] += g; g2s[j] += g * g;
            }
        }
        #pragma unroll
        for (int j = 0; j < 3; j++)
            for (int off = 32; off; off >>= 1) {
                g1[j] += __shfl_xor(g1[j], off);
                g2s[j] += __shfl_xor(g2s[j], off);
            }
        __shared__ float redg[4][6];
        if (lane == 0) {
            #pragma unroll
            for (int j = 0; j < 3; j++) { redg[wv][j] = g1[j]; redg[wv][3 + j] = g2s[j]; }
        }
        __syncthreads();
        if (tid < 6)
            gnstats[tid] = redg[0][tid] + redg[1][tid] + redg[2][tid] + redg[3][tid];
    }
}

// ---------------------------------------------------------------------------
__device__ __forceinline__ void d1_coefs(
    const float* c1stats, const float* gnstats,
    const float* d1g, const float* d1be, float* scd, float* shd)
{
    #pragma unroll
    for (int j = 0; j < 3; j++) {
        float mc = c1stats[j] * (1.f / 16.f), qc = c1stats[3 + j] * (1.f / 16.f);
        float mg = gnstats[j] * (1.f / 8192.f), qg = gnstats[3 + j] * (1.f / 8192.f);
        float m = mc + mg;
        float var = fmaxf((qc - mc * mc) + (qg - mg * mg), 0.f);
        float sc = d1g[j] * rsqrtf(var + EPSBN);
        scd[j] = sc;
        shd[j] = d1be[j] - m * sc;
    }
}

// ---------------------------------------------------------------------------
__global__ __launch_bounds__(256) void k_d2stats(
    const float* __restrict__ c1, const float* __restrict__ c2, const float* __restrict__ gn,
    const float* __restrict__ c1stats, const float* __restrict__ gnstats,
    const float* __restrict__ d1g, const float* __restrict__ d1be,
    const float* __restrict__ d2w, const float* __restrict__ d2b,
    float* __restrict__ statsd2)
{
    int gid = blockIdx.x * 256 + threadIdx.x;
    int b = gid >> 13, n = gid & 8191;
    int lane = threadIdx.x & 63, wv = threadIdx.x >> 6;
    float scd[3], shd[3];
    d1_coefs(c1stats, gnstats, d1g, d1be, scd, shd);
    float z3[3];
    #pragma unroll
    for (int j = 0; j < 3; j++)
        z3[j] = fmaxf(scd[j] * (c1[b * 3 + j] + gn[n * 3 + j]) + shd[j], 0.f);
    float vals[6];
    #pragma unroll
    for (int u = 0; u < 3; u++) {
        float a = c2[b * 3 + u]
                + z3[0] * d2w[512 * 3 + u]
                + z3[1] * d2w[513 * 3 + u]
                + z3[2] * d2w[514 * 3 + u]
                + d2b[u];
        vals[u] = a; vals[3 + u] = a * a;
    }
    #pragma unroll
    for (int j = 0; j < 6; j++)
        for (int off = 32; off; off >>= 1) vals[j] += __shfl_xor(vals[j], off);
    __shared__ float red[4][6];
    if (lane == 0) {
        #pragma unroll
        for (int j = 0; j < 6; j++) red[wv][j] = vals[j];
    }
    __syncthreads();
    if (threadIdx.x < 6)
        atomicAdd(statsd2 + threadIdx.x,
                  red[0][threadIdx.x] + red[1][threadIdx.x] + red[2][threadIdx.x] + red[3][threadIdx.x]);
}

// ---------------------------------------------------------------------------
__global__ __launch_bounds__(256) void k_out(
    const float* __restrict__ c1, const float* __restrict__ c2, const float* __restrict__ gn,
    const float* __restrict__ c1stats, const float* __restrict__ gnstats,
    const float* __restrict__ statsd2,
    const float* __restrict__ d1g, const float* __restrict__ d1be,
    const float* __restrict__ d2w, const float* __restrict__ d2b,
    const float* __restrict__ d2g, const float* __restrict__ d2be,
    float* __restrict__ out)
{
    int gid = blockIdx.x * 256 + threadIdx.x;
    int b = gid >> 13, n = gid & 8191;
    float scd[3], shd[3];
    d1_coefs(c1stats, gnstats, d1g, d1be, scd, shd);
    float z3[3];
    #pragma unroll
    for (int j = 0; j < 3; j++)
        z3[j] = fmaxf(scd[j] * (c1[b * 3 + j] + gn[n * 3 + j]) + shd[j], 0.f);
    #pragma unroll
    for (int u = 0; u < 3; u++) {
        float a = c2[b * 3 + u]
                + z3[0] * d2w[512 * 3 + u]
                + z3[1] * d2w[513 * 3 + u]
                + z3[2] * d2w[514 * 3 + u]
                + d2b[u];
        float m2 = statsd2[u] * (1.f / (float)NROWS);
        float v2 = fmaxf(statsd2[3 + u] * (1.f / (float)NROWS) - m2 * m2, 0.f);
        float sc = d2g[u] * rsqrtf(v2 + EPSBN);
        float sh = d2be[u] - m2 * sc;
        out[(size_t)gid * 3 + u] = fmaxf(sc * a + sh, 0.f);
    }
}

// ---------------------------------------------------------------------------
extern "C" void kernel_launch(void* const* d_in, const int* in_sizes, int n_in,
                              void* d_out, int out_size, void* d_ws, size_t ws_size,
                              hipStream_t stream)
{
    (void)in_sizes; (void)n_in; (void)out_size; (void)ws_size;
    const float* data = (const float*)d_in[0];
    const int*   knn  = (const int*)d_in[1];
    const float* e1w = (const float*)d_in[2],  *e1b = (const float*)d_in[3];
    const float* e1g = (const float*)d_in[4],  *e1be = (const float*)d_in[5];
    const float* gc1w = (const float*)d_in[6], *gc1b = (const float*)d_in[7];
    const float* g1g = (const float*)d_in[8],  *g1be = (const float*)d_in[9];
    const float* gc2w = (const float*)d_in[10], *gc2b = (const float*)d_in[11];
    const float* g2g = (const float*)d_in[12], *g2be = (const float*)d_in[13];
    const float* e2w = (const float*)d_in[14], *e2b = (const float*)d_in[15];
    const float* e2g = (const float*)d_in[16], *e2be = (const float*)d_in[17];
    const float* d1w = (const float*)d_in[18], *d1b = (const float*)d_in[19];
    const float* d1g = (const float*)d_in[20], *d1be = (const float*)d_in[21];
    const float* d2w = (const float*)d_in[22], *d2b = (const float*)d_in[23];
    const float* d2g = (const float*)d_in[24], *d2be = (const float*)d_in[25];

    char* p = (char*)d_ws;
    auto alloc = [&](size_t bytes) -> void* {
        void* r = (void*)p;
        p += (bytes + 255) & ~(size_t)255;
        return r;
    };
    unsigned short* a1  = (unsigned short*)alloc((size_t)NROWS * 64 * 2);  // 16.8 MB fp16
    unsigned short* a2h = (unsigned short*)alloc((size_t)NROWS * 128 * 2); // 33.5 MB fp16
    unsigned short* s1  = (unsigned short*)alloc((size_t)NROWS * 64 * 2);  // 16.8 MB fp16
    unsigned short* s2  = (unsigned short*)alloc((size_t)NROWS * 128 * 2); // 33.5 MB fp16
    float4* data4 = (float4*)alloc((size_t)NROWS * 16);                    // 2 MB
    unsigned short* W1T = (unsigned short*)alloc(8192 * 2);
    unsigned short* W2T = (unsigned short*)alloc(65536 * 2);
    float* statszone = (float*)alloc(SZ_TOT * 4);
    float* stats1  = statszone + SZ_S1;
    float* stats2p = statszone + SZ_S2P;
    float* stats3p = statszone + SZ_S3P;
    float* stats4  = statszone + SZ_S4;
    float* c1stats = statszone + SZ_C1;
    float* gnstats = statszone + SZ_GN;
    float* statsd2 = statszone + SZ_D2;
    float* scsh1   = statszone + SZ_SCSH1;
    float* scsh2   = statszone + SZ_SCSH2;
    unsigned* mm = (unsigned*)alloc(16384 * 4);
    float* a4 = (float*)alloc(16 * 512 * 4);
    float* c1 = (float*)alloc(64 * 4);
    float* c2 = (float*)alloc(64 * 4);
    float* gn = (float*)alloc(8192 * 3 * 4);

    k_prep<<<128, 256, 0, stream>>>(data, gc1w, gc2w, d1w, d1b, W1T, W2T, gn,
                                    statszone, mm, data4);
    k_cov_e1<<<512, 256, 0, stream>>>(data4, knn, e1w, e1b, a1);
    k_reduce_a1<<<256, 256, 0, stream>>>(a1, stats1);
    k_bncoef<64, 1><<<1, 256, 0, stream>>>(stats1, e1g, e1be, scsh1);
    k_gather16<64><<<NROWS / 64, 256, 0, stream>>>(a1, knn, scsh1, s1);
    k_gemm<64, 128, 1, true><<<1024, 256, 0, stream>>>(s1, W1T, gc1b, a2h, stats2p, nullptr);
    k_bncoef<128, 64><<<1, 256, 0, stream>>>(stats2p, g1g, g1be, scsh2);
    k_gather16<128><<<NROWS / 32, 256, 0, stream>>>(a2h, knn, scsh2, s2);
    k_gemm<128, 512, 4, false><<<4096, 256, 0, stream>>>(s2, W2T, gc2b, nullptr, stats3p, mm);
    k_e2<<<128, 256, 0, stream>>>(stats3p, mm, g2g, g2be, e2w, e2b, a4, stats4);
    k_code<<<16, 256, 0, stream>>>(a4, stats4, e2g, e2be, d1w, d2w, gn, c1, c2, c1stats, gnstats);
    k_d2stats<<<512, 256, 0, stream>>>(c1, c2, gn, c1stats, gnstats, d1g, d1be, d2w, d2b, statsd2);
    k_out<<<512, 256, 0, stream>>>(c1, c2, gn, c1stats, gnstats, statsd2,
                                   d1g, d1be, d2w, d2b, d2g, d2be, (float*)d_out);
}